// Round 1
// baseline (131.345 us; speedup 1.0000x reference)
//
#include <hip/hip_runtime.h>
#include <hip/hip_bf16.h>
#include <stdint.h>

#define NUM_EMBED 1024
#define EMBED_DIM 256
#define BATCH     32
#define HW        1024            // 32*32
#define N_ROWS    32768           // BATCH*HW
#define OUT_ELEMS 8388608         // N_ROWS*EMBED_DIM

typedef __bf16 bf16x8 __attribute__((ext_vector_type(8)));
typedef float  f32x4  __attribute__((ext_vector_type(4)));

typedef unsigned short ushort_t;

static __device__ __forceinline__ ushort_t f2bf(float f) {
    union { float f; uint32_t u; } v;
    v.f = f;
    uint32_t u = v.u;
    u += 0x7FFFu + ((u >> 16) & 1u);   // round-to-nearest-even
    return (ushort_t)(u >> 16);
}

// ---------------------------------------------------------------------------
// K0: zero the two fp64 accumulators (d_ws is poisoned 0xAA before each call)
// ---------------------------------------------------------------------------
__global__ void k_init(double* sums) {
    if (threadIdx.x < 2) sums[threadIdx.x] = 0.0;
}

// ---------------------------------------------------------------------------
// K1: out = x (exact copy), Xbf[n][c] = bf16(x[b][c][h][w]) transposed,
//     sums[0] += sum(x^2)
// Block: 256 threads. Tile: one batch b, 32 channels x 256 hw positions.
// Grid: 32 b * 8 ctiles * 4 hwtiles = 1024 blocks.
// ---------------------------------------------------------------------------
__global__ __launch_bounds__(256) void k_transpose(
        const float* __restrict__ x, float* __restrict__ out,
        ushort_t* __restrict__ xbf, double* __restrict__ sums) {
    __shared__ ushort_t tile[32][257];
    __shared__ float wsum[4];

    int bid = blockIdx.x;
    int b  = bid >> 5;
    int ct = (bid >> 2) & 7;
    int ht = bid & 3;
    int c0  = ct * 32;
    int hw0 = ht * 256;
    int t = threadIdx.x;

    const float* xb = x   + (size_t)b * (EMBED_DIM * HW) + hw0 + t;
    float*       ob = out + (size_t)b * (EMBED_DIM * HW) + hw0 + t;

    float acc = 0.f;
    #pragma unroll
    for (int i = 0; i < 32; ++i) {
        float v = xb[(size_t)(c0 + i) * HW];
        ob[(size_t)(c0 + i) * HW] = v;
        acc += v * v;
        tile[i][t] = f2bf(v);
    }
    __syncthreads();

    // write 32 consecutive bf16 (64B) per thread, vectorized as 4x uint4
    int n = b * HW + hw0 + t;
    uint32_t uu[16];
    #pragma unroll
    for (int j = 0; j < 16; ++j)
        uu[j] = (uint32_t)tile[2 * j][t] | ((uint32_t)tile[2 * j + 1][t] << 16);
    uint4* dst = reinterpret_cast<uint4*>(xbf + (size_t)n * EMBED_DIM + c0);
    #pragma unroll
    for (int q = 0; q < 4; ++q) {
        uint4 v;
        v.x = uu[4 * q + 0]; v.y = uu[4 * q + 1];
        v.z = uu[4 * q + 2]; v.w = uu[4 * q + 3];
        dst[q] = v;
    }

    // block-reduce sum(x^2), one fp64 atomic per block
    #pragma unroll
    for (int off = 32; off; off >>= 1) acc += __shfl_down(acc, off);
    if ((t & 63) == 0) wsum[t >> 6] = acc;
    __syncthreads();
    if (t == 0)
        atomicAdd(&sums[0], (double)(wsum[0] + wsum[1] + wsum[2] + wsum[3]));
}

// ---------------------------------------------------------------------------
// K2: Ebf[k][c] = bf16(codebook[k][c]), enorm[k] = ||e_k||^2 (fp32 exact)
// One wave per code; grid 256 blocks x 256 threads.
// ---------------------------------------------------------------------------
__global__ __launch_bounds__(256) void k_codeprep(
        const float* __restrict__ cb, ushort_t* __restrict__ ebf,
        float* __restrict__ enorm) {
    int t = threadIdx.x;
    int w = t >> 6, lane = t & 63;
    int k = blockIdx.x * 4 + w;

    const float4 v = *reinterpret_cast<const float4*>(cb + (size_t)k * EMBED_DIM + lane * 4);
    float ss = v.x * v.x + v.y * v.y + v.z * v.z + v.w * v.w;

    uint2 pk;
    pk.x = (uint32_t)f2bf(v.x) | ((uint32_t)f2bf(v.y) << 16);
    pk.y = (uint32_t)f2bf(v.z) | ((uint32_t)f2bf(v.w) << 16);
    *reinterpret_cast<uint2*>(ebf + (size_t)k * EMBED_DIM + lane * 4) = pk;

    #pragma unroll
    for (int off = 32; off; off >>= 1) ss += __shfl_down(ss, off);
    if (lane == 0) enorm[k] = ss;
}

// ---------------------------------------------------------------------------
// K3: per-row min_k(||e_k||^2 - 2 x.e_k) via bf16 MFMA, sums[1] += sum of mins
// Block: 256 threads (4 waves), 64 rows. Wave w: rows (w&1)*32..+31,
// code-parity p=w>>1 (codes ci*64 + p*32 + [0,32) over 16 chunks).
// Grid: 512 blocks.
// ---------------------------------------------------------------------------
__global__ __launch_bounds__(256) void k_argmin(
        const ushort_t* __restrict__ xbf, const ushort_t* __restrict__ ebf,
        const float* __restrict__ enorm, double* __restrict__ sums) {
    // row stride 264 (=256+8) bf16 => 528B = 132 dwords = 4 banks offset/row:
    // breaks the 512B power-of-2 stride conflict, keeps 16B alignment.
    __shared__ ushort_t Xs[64][264];
    __shared__ ushort_t Es[2][32][264];
    __shared__ float red[64][2];

    int t = threadIdx.x;
    int w = t >> 6, lane = t & 63;
    int quad = lane >> 4, l16 = lane & 15;
    int mbase = (w & 1) * 32;
    int p = w >> 1;
    int r0 = blockIdx.x * 64;

    // stage X tile (64 rows x 256 bf16), 8 x uint4 per thread
    {
        const uint4* src = reinterpret_cast<const uint4*>(xbf + (size_t)r0 * EMBED_DIM);
        #pragma unroll
        for (int i = 0; i < 8; ++i) {
            int g = t + i * 256;            // 0..2047
            int row = g >> 5, cg = g & 31;  // row stride = 32 uint4 in src
            *reinterpret_cast<uint4*>(&Xs[row][cg * 8]) = src[g];
        }
    }

    float dmin[2][4];
    #pragma unroll
    for (int mt = 0; mt < 2; ++mt)
        #pragma unroll
        for (int r = 0; r < 4; ++r) dmin[mt][r] = 1e30f;

    for (int ci = 0; ci < 16; ++ci) {
        __syncthreads();   // previous chunk's compute done (also covers Xs load at ci=0)
        {   // stage 64 codes (both parities), 8 x uint4 per thread
            int cbase = ci * 64;
            const uint4* esrc = reinterpret_cast<const uint4*>(ebf + (size_t)cbase * EMBED_DIM);
            #pragma unroll
            for (int i = 0; i < 8; ++i) {
                int g = t + i * 256;            // 0..2047
                int code = g >> 5, cg = g & 31; // code 0..63 within chunk
                *reinterpret_cast<uint4*>(&Es[code >> 5][code & 31][cg * 8]) = esrc[g];
            }
        }
        __syncthreads();

        f32x4 zero = {0.f, 0.f, 0.f, 0.f};
        f32x4 acc00 = zero, acc01 = zero, acc10 = zero, acc11 = zero;
        #pragma unroll
        for (int kk = 0; kk < 8; ++kk) {
            int k0 = kk * 32 + quad * 8;
            bf16x8 a0 = *reinterpret_cast<const bf16x8*>(&Xs[mbase + l16][k0]);
            bf16x8 a1 = *reinterpret_cast<const bf16x8*>(&Xs[mbase + 16 + l16][k0]);
            bf16x8 b0 = *reinterpret_cast<const bf16x8*>(&Es[p][l16][k0]);
            bf16x8 b1 = *reinterpret_cast<const bf16x8*>(&Es[p][16 + l16][k0]);
            acc00 = __builtin_amdgcn_mfma_f32_16x16x32_bf16(a0, b0, acc00, 0, 0, 0);
            acc01 = __builtin_amdgcn_mfma_f32_16x16x32_bf16(a0, b1, acc01, 0, 0, 0);
            acc10 = __builtin_amdgcn_mfma_f32_16x16x32_bf16(a1, b0, acc10, 0, 0, 0);
            acc11 = __builtin_amdgcn_mfma_f32_16x16x32_bf16(a1, b1, acc11, 0, 0, 0);
        }

        // chunk epilogue: dist = ||e||^2 - 2*dot ; running min
        int codeA = ci * 64 + p * 32 + l16;   // nt=0 column for this lane
        float en0 = enorm[codeA];
        float en1 = enorm[codeA + 16];
        #pragma unroll
        for (int r = 0; r < 4; ++r) {
            float d00 = en0 - 2.f * acc00[r];
            float d01 = en1 - 2.f * acc01[r];
            float d10 = en0 - 2.f * acc10[r];
            float d11 = en1 - 2.f * acc11[r];
            dmin[0][r] = fminf(dmin[0][r], fminf(d00, d01));
            dmin[1][r] = fminf(dmin[1][r], fminf(d10, d11));
        }
    }

    // reduce min across the 16 columns (lanes sharing the same rows)
    #pragma unroll
    for (int mt = 0; mt < 2; ++mt)
        #pragma unroll
        for (int r = 0; r < 4; ++r) {
            float v = dmin[mt][r];
            v = fminf(v, __shfl_xor(v, 1));
            v = fminf(v, __shfl_xor(v, 2));
            v = fminf(v, __shfl_xor(v, 4));
            v = fminf(v, __shfl_xor(v, 8));
            dmin[mt][r] = v;
        }

    __syncthreads();
    if (l16 == 0) {
        #pragma unroll
        for (int mt = 0; mt < 2; ++mt)
            #pragma unroll
            for (int r = 0; r < 4; ++r) {
                int row = mbase + mt * 16 + quad * 4 + r;
                red[row][p] = dmin[mt][r];
            }
    }
    __syncthreads();

    if (t < 64) {
        float d = fminf(red[t][0], red[t][1]);
        #pragma unroll
        for (int off = 32; off; off >>= 1) d += __shfl_down(d, off);
        if (t == 0) atomicAdd(&sums[1], (double)d);
    }
}

// ---------------------------------------------------------------------------
// K4: loss = 1.25 * (sum(x^2) + sum(dmin)) / (N_ROWS*EMBED_DIM)
// ---------------------------------------------------------------------------
__global__ void k_finalize(const double* __restrict__ sums, float* __restrict__ loss_out) {
    loss_out[0] = (float)(1.25 * (sums[0] + sums[1]) / (double)OUT_ELEMS);
}

extern "C" void kernel_launch(void* const* d_in, const int* in_sizes, int n_in,
                              void* d_out, int out_size, void* d_ws, size_t ws_size,
                              hipStream_t stream) {
    const float* x  = (const float*)d_in[0];   // [32,256,32,32] fp32
    const float* cb = (const float*)d_in[1];   // [1024,256] fp32
    float* out = (float*)d_out;                // 8388608 outs + 1 loss

    char* ws = (char*)d_ws;
    double*   sums  = (double*)ws;                 // 16 B
    float*    enorm = (float*)(ws + 256);          // 4 KB
    ushort_t* ebf   = (ushort_t*)(ws + 8192);      // 512 KB
    ushort_t* xbf   = (ushort_t*)(ws + 1048576);   // 16 MB

    hipLaunchKernelGGL(k_init,      dim3(1),    dim3(64),  0, stream, sums);
    hipLaunchKernelGGL(k_transpose, dim3(1024), dim3(256), 0, stream, x, out, xbf, sums);
    hipLaunchKernelGGL(k_codeprep,  dim3(256),  dim3(256), 0, stream, cb, ebf, enorm);
    hipLaunchKernelGGL(k_argmin,    dim3(512),  dim3(256), 0, stream, xbf, ebf, enorm, sums);
    hipLaunchKernelGGL(k_finalize,  dim3(1),    dim3(1),   0, stream, sums, out + OUT_ELEMS);
}

// Round 2
// 117.639 us; speedup vs baseline: 1.1165x; 1.1165x over previous
//
#include <hip/hip_runtime.h>
#include <hip/hip_bf16.h>
#include <stdint.h>

#define NUM_EMBED 1024
#define EMBED_DIM 256
#define BATCH     32
#define HW        1024            // 32*32
#define N_ROWS    32768           // BATCH*HW
#define OUT_ELEMS 8388608         // N_ROWS*EMBED_DIM

typedef __bf16 bf16x8 __attribute__((ext_vector_type(8)));
typedef float  f32x4  __attribute__((ext_vector_type(4)));
typedef unsigned short ushort_t;

static __device__ __forceinline__ ushort_t f2bf(float f) {
    union { float f; uint32_t u; } v;
    v.f = f;
    uint32_t u = v.u;
    u += 0x7FFFu + ((u >> 16) & 1u);   // round-to-nearest-even
    return (ushort_t)(u >> 16);
}

// async global->LDS, 16B per lane. LDS dest must be wave-uniform base + lane*16.
static __device__ __forceinline__ void gl_lds16(const void* g, void* l) {
    __builtin_amdgcn_global_load_lds(
        (const __attribute__((address_space(1))) void*)g,
        (__attribute__((address_space(3))) void*)l, 16, 0, 0);
}

// ---------------------------------------------------------------------------
// Fragment layouts (bf16, 16B = 8 elems per lane slot):
//   X (A-operand): idx4 = ((n16*8 + kk)*64 + quad*16 + l16)
//                  holds X[row = n16*16 + l16][k = kk*32 + quad*8 + j]
//   E (B-operand): idx4 = ((k16*8 + kk)*64 + quad*16 + l16)
//                  holds E[code = k16*16 + l16][k = kk*32 + quad*8 + j]
// ---------------------------------------------------------------------------

// ---------------------------------------------------------------------------
// K1: codebook -> bf16 fragment layout + enorm[k] = ||e_k||^2
// grid 64 blocks (one 16-code tile each) x 256 threads.
// ---------------------------------------------------------------------------
__global__ __launch_bounds__(256) void k_codeprep(
        const float* __restrict__ cb, ushort_t* __restrict__ ebf,
        float* __restrict__ enorm) {
    int t = threadIdx.x;
    int k16 = blockIdx.x;
    int kr = t >> 4;              // code within tile (l16 of code)
    int s  = t & 15;              // channel group: c = 16*s + m
    int k = k16 * 16 + kr;

    const float4* src = reinterpret_cast<const float4*>(cb + (size_t)k * EMBED_DIM + s * 16);
    float f[16];
    float4 v0 = src[0], v1 = src[1], v2 = src[2], v3 = src[3];
    f[0]=v0.x; f[1]=v0.y; f[2]=v0.z; f[3]=v0.w;
    f[4]=v1.x; f[5]=v1.y; f[6]=v1.z; f[7]=v1.w;
    f[8]=v2.x; f[9]=v2.y; f[10]=v2.z; f[11]=v2.w;
    f[12]=v3.x; f[13]=v3.y; f[14]=v3.z; f[15]=v3.w;

    float ss = 0.f;
    #pragma unroll
    for (int m = 0; m < 16; ++m) ss += f[m] * f[m];

    uint32_t uu[8];
    #pragma unroll
    for (int m = 0; m < 8; ++m)
        uu[m] = (uint32_t)f2bf(f[2 * m]) | ((uint32_t)f2bf(f[2 * m + 1]) << 16);

    int kk = s >> 1;
    int qb = 2 * (s & 1);
    uint4* dst = reinterpret_cast<uint4*>(ebf);
    uint4 w0; w0.x = uu[0]; w0.y = uu[1]; w0.z = uu[2]; w0.w = uu[3];
    uint4 w1; w1.x = uu[4]; w1.y = uu[5]; w1.z = uu[6]; w1.w = uu[7];
    dst[((size_t)k16 * 8 + kk) * 64 + (qb + 0) * 16 + kr] = w0;
    dst[((size_t)k16 * 8 + kk) * 64 + (qb + 1) * 16 + kr] = w1;

    // sum ss across the 16 channel-group lanes (consecutive lanes, same wave)
    #pragma unroll
    for (int off = 1; off < 16; off <<= 1) ss += __shfl_xor(ss, off);
    if (s == 0) enorm[k] = ss;
}

// ---------------------------------------------------------------------------
// K2: out = x (exact copy), xbf = bf16(x) in A-fragment layout,
//     psumA[block] = partial sum(x^2)
// grid 1024 = 32 b * 8 ct (kk) * 4 ht, 256 threads.
// ---------------------------------------------------------------------------
__global__ __launch_bounds__(256) void k_transpose(
        const float* __restrict__ x, float* __restrict__ out,
        ushort_t* __restrict__ xbf, float* __restrict__ psumA) {
    __shared__ ushort_t tile[32][257];
    __shared__ float wsum[4];

    int bid = blockIdx.x;
    int b  = bid >> 5;
    int ct = (bid >> 2) & 7;      // this is kk for the fragment layout
    int ht = bid & 3;
    int c0  = ct * 32;
    int hw0 = ht * 256;
    int t = threadIdx.x;

    const float* xb = x   + (size_t)b * (EMBED_DIM * HW) + hw0 + t;
    float*       ob = out + (size_t)b * (EMBED_DIM * HW) + hw0 + t;

    float acc = 0.f;
    #pragma unroll
    for (int i = 0; i < 32; ++i) {
        float v = xb[(size_t)(c0 + i) * HW];
        ob[(size_t)(c0 + i) * HW] = v;
        acc += v * v;
        tile[i][t] = f2bf(v);
    }
    __syncthreads();

    int n = b * HW + hw0 + t;
    int n16 = n >> 4;
    int l16 = t & 15;
    uint32_t uu[16];
    #pragma unroll
    for (int j = 0; j < 16; ++j)
        uu[j] = (uint32_t)tile[2 * j][t] | ((uint32_t)tile[2 * j + 1][t] << 16);
    uint4* dst = reinterpret_cast<uint4*>(xbf);
    #pragma unroll
    for (int q = 0; q < 4; ++q) {
        uint4 v;
        v.x = uu[4 * q + 0]; v.y = uu[4 * q + 1];
        v.z = uu[4 * q + 2]; v.w = uu[4 * q + 3];
        dst[((size_t)n16 * 8 + ct) * 64 + q * 16 + l16] = v;
    }

    #pragma unroll
    for (int off = 32; off; off >>= 1) acc += __shfl_down(acc, off);
    if ((t & 63) == 0) wsum[t >> 6] = acc;
    __syncthreads();
    if (t == 0) psumA[bid] = wsum[0] + wsum[1] + wsum[2] + wsum[3];
}

// ---------------------------------------------------------------------------
// K3: per-row min_k(||e_k||^2 - 2 x.e_k), psumB[block] = sum of row-mins.
// 256 blocks x 256 threads (4 waves). Wave owns 32 rows, A-frags in regs.
// E streamed in 64-code chunks, double-buffered LDS via global_load_lds.
// ---------------------------------------------------------------------------
__global__ __launch_bounds__(256, 2) void k_argmin(
        const ushort_t* __restrict__ xbf, const ushort_t* __restrict__ ebf,
        const float* __restrict__ enorm, float* __restrict__ psumB) {
    __shared__ ushort_t Es[2][64 * 256];   // 2 x 32 KB, fragment layout
    __shared__ float en_s[NUM_EMBED];      // 4 KB
    __shared__ float red[4];

    int t = threadIdx.x;
    int w = t >> 6, lane = t & 63;
    int l16 = lane & 15;
    int r0 = blockIdx.x * 128;

    // enorm -> LDS (covered by the first barrier)
    #pragma unroll
    for (int i = 0; i < 4; ++i) en_s[t + i * 256] = enorm[t + i * 256];

    // A fragments: rows r0 + w*32 + [0,32)
    int n16b = (r0 >> 4) + 2 * w;
    bf16x8 a[2][8];
    const uint4* xsrc = reinterpret_cast<const uint4*>(xbf);
    #pragma unroll
    for (int mt = 0; mt < 2; ++mt)
        #pragma unroll
        for (int kk = 0; kk < 8; ++kk) {
            uint4 v = xsrc[((size_t)(n16b + mt) * 8 + kk) * 64 + lane];
            a[mt][kk] = *reinterpret_cast<bf16x8*>(&v);
        }

    // stage chunk 0 (32 KB): 8 x 16B per thread, contiguous
    const char* esrc = reinterpret_cast<const char*>(ebf);
    {
        char* ldst = (char*)&Es[0][0];
        #pragma unroll
        for (int i = 0; i < 8; ++i) {
            int off = (i * 256 + t) * 16;
            gl_lds16(esrc + off, ldst + off);
        }
    }
    __syncthreads();

    float dmin[2][4];
    #pragma unroll
    for (int mt = 0; mt < 2; ++mt)
        #pragma unroll
        for (int r = 0; r < 4; ++r) dmin[mt][r] = 1e30f;

    for (int ci = 0; ci < 16; ++ci) {
        // prefetch next chunk into the other buffer (drained by end-of-loop barrier)
        if (ci + 1 < 16) {
            const char* s = esrc + (size_t)(ci + 1) * 32768;
            char* ldst = (char*)&Es[(ci + 1) & 1][0];
            #pragma unroll
            for (int i = 0; i < 8; ++i) {
                int off = (i * 256 + t) * 16;
                gl_lds16(s + off, ldst + off);
            }
        }

        const ushort_t* buf = &Es[ci & 1][0];
        f32x4 acc[2][4];
        #pragma unroll
        for (int mt = 0; mt < 2; ++mt)
            #pragma unroll
            for (int ct = 0; ct < 4; ++ct) {
                f32x4 z = {0.f, 0.f, 0.f, 0.f};
                acc[mt][ct] = z;
            }

        #pragma unroll
        for (int kk = 0; kk < 8; ++kk) {
            bf16x8 bfr[4];
            #pragma unroll
            for (int ct = 0; ct < 4; ++ct)
                bfr[ct] = *reinterpret_cast<const bf16x8*>(&buf[(((ct * 8) + kk) * 64 + lane) * 8]);
            #pragma unroll
            for (int mt = 0; mt < 2; ++mt)
                #pragma unroll
                for (int ct = 0; ct < 4; ++ct)
                    acc[mt][ct] = __builtin_amdgcn_mfma_f32_16x16x32_bf16(
                        a[mt][kk], bfr[ct], acc[mt][ct], 0, 0, 0);
        }

        // dist = ||e||^2 - 2*dot; running min. col (code) = ci*64 + ct*16 + l16
        #pragma unroll
        for (int ct = 0; ct < 4; ++ct) {
            float en = en_s[ci * 64 + ct * 16 + l16];
            #pragma unroll
            for (int mt = 0; mt < 2; ++mt)
                #pragma unroll
                for (int r = 0; r < 4; ++r)
                    dmin[mt][r] = fminf(dmin[mt][r], fmaf(-2.f, acc[mt][ct][r], en));
        }

        __syncthreads();   // all waves done with buf; prefetch (vmcnt) drained
    }

    // reduce min across the 16 columns sharing each row (l16 bits only)
    #pragma unroll
    for (int mt = 0; mt < 2; ++mt)
        #pragma unroll
        for (int r = 0; r < 4; ++r) {
            float v = dmin[mt][r];
            v = fminf(v, __shfl_xor(v, 1));
            v = fminf(v, __shfl_xor(v, 2));
            v = fminf(v, __shfl_xor(v, 4));
            v = fminf(v, __shfl_xor(v, 8));
            dmin[mt][r] = v;
        }

    // wave sum of its 32 distinct row-mins (l16==0 lanes hold quad's rows)
    float s = 0.f;
    if (l16 == 0) {
        #pragma unroll
        for (int mt = 0; mt < 2; ++mt)
            #pragma unroll
            for (int r = 0; r < 4; ++r) s += dmin[mt][r];
    }
    s += __shfl_down(s, 16);
    s += __shfl_down(s, 32);
    if (lane == 0) red[w] = s;
    __syncthreads();
    if (t == 0) psumB[blockIdx.x] = red[0] + red[1] + red[2] + red[3];
}

// ---------------------------------------------------------------------------
// K4: loss = 1.25 * (sum(x^2) + sum(dmin)) / OUT_ELEMS
// ---------------------------------------------------------------------------
__global__ __launch_bounds__(256) void k_finalize(
        const float* __restrict__ psumA, const float* __restrict__ psumB,
        float* __restrict__ loss_out) {
    __shared__ double wsd[4];
    int t = threadIdx.x;
    double s = (double)psumA[t] + (double)psumA[t + 256]
             + (double)psumA[t + 512] + (double)psumA[t + 768]
             + (double)psumB[t];
    #pragma unroll
    for (int off = 32; off; off >>= 1) s += __shfl_down(s, off);
    if ((t & 63) == 0) wsd[t >> 6] = s;
    __syncthreads();
    if (t == 0)
        loss_out[0] = (float)(1.25 * (wsd[0] + wsd[1] + wsd[2] + wsd[3]) / (double)OUT_ELEMS);
}

extern "C" void kernel_launch(void* const* d_in, const int* in_sizes, int n_in,
                              void* d_out, int out_size, void* d_ws, size_t ws_size,
                              hipStream_t stream) {
    const float* x  = (const float*)d_in[0];   // [32,256,32,32] fp32
    const float* cb = (const float*)d_in[1];   // [1024,256] fp32
    float* out = (float*)d_out;                // 8388608 outs + 1 loss

    char* ws = (char*)d_ws;
    float*    psumA = (float*)ws;                  // 4 KB (1024)
    float*    psumB = (float*)(ws + 4096);         // 1 KB (256)
    float*    enorm = (float*)(ws + 8192);         // 4 KB
    ushort_t* ebf   = (ushort_t*)(ws + 16384);     // 512 KB
    ushort_t* xbf   = (ushort_t*)(ws + 1048576);   // 16 MB

    hipLaunchKernelGGL(k_codeprep,  dim3(64),   dim3(256), 0, stream, cb, ebf, enorm);
    hipLaunchKernelGGL(k_transpose, dim3(1024), dim3(256), 0, stream, x, out, xbf, psumA);
    hipLaunchKernelGGL(k_argmin,    dim3(256),  dim3(256), 0, stream, xbf, ebf, enorm, psumB);
    hipLaunchKernelGGL(k_finalize,  dim3(1),    dim3(256), 0, stream, psumA, psumB, out + OUT_ELEMS);
}

// Round 3
// 114.130 us; speedup vs baseline: 1.1508x; 1.0307x over previous
//
#include <hip/hip_runtime.h>
#include <hip/hip_bf16.h>
#include <stdint.h>

#define NUM_EMBED 1024
#define EMBED_DIM 256
#define HW        1024            // 32*32
#define N_ROWS    32768
#define OUT_ELEMS 8388608
#define ARG_BLOCKS 256

typedef float f32x4 __attribute__((ext_vector_type(4)));

// async global->LDS, 16B per lane (wave-uniform base + lane*16)
static __device__ __forceinline__ void gl_lds16(const void* g, void* l) {
    __builtin_amdgcn_global_load_lds(
        (const __attribute__((address_space(1))) void*)g,
        (__attribute__((address_space(3))) void*)l, 16, 0, 0);
}

// pack 4 floats -> 4 fp8 e4m3 (one dword), RNE via v_cvt_pk_fp8_f32
static __device__ __forceinline__ uint32_t pk4_fp8(float a, float b, float c, float d) {
    int r = __builtin_amdgcn_cvt_pk_fp8_f32(a, b, 0, false);
    r = __builtin_amdgcn_cvt_pk_fp8_f32(c, d, r, true);
    return (uint32_t)r;
}

// ---------------------------------------------------------------------------
// fp8 fragment layouts (8B = 8 e4m3 per lane-slot, k = kk*32 + quad*8 + j):
//   X: idx8B = (n16*8 + kk)*64 + quad*16 + l16   (row = n16*16 + l16)
//   E: idx8B = (k16*8 + kk)*64 + quad*16 + l16   (code = k16*16 + l16)
// E is pre-scaled by 1024 (values ~uniform(-1,1), e4m3 normal range).
// ---------------------------------------------------------------------------

// ---------------------------------------------------------------------------
// K1 fused prep: blocks 0..63 = codebook->fp8 frags + enorm (+ticket=0);
//                blocks 64..1087 = out=x copy + x->fp8 frags + psumA.
// ---------------------------------------------------------------------------
__global__ __launch_bounds__(256) void k_prep(
        const float* __restrict__ x, const float* __restrict__ cb,
        float* __restrict__ out, uint8_t* __restrict__ ef8,
        float* __restrict__ enorm, uint8_t* __restrict__ xf8,
        float* __restrict__ psumA, int* __restrict__ ticket) {
    __shared__ float wsum[4];
    int bid = blockIdx.x;
    int t = threadIdx.x;

    if (bid < 64) {
        // ---- codebook prep: block = one 16-code tile ----
        if (bid == 0 && t == 0) *ticket = 0;
        int k16 = bid;
        int kr = t >> 4;          // code within tile (= l16 of the fragment)
        int s  = t & 15;          // k-segment: k = s*16 .. +16
        int code = k16 * 16 + kr;

        const float4* src = reinterpret_cast<const float4*>(
            cb + (size_t)code * EMBED_DIM + s * 16);
        float4 v0 = src[0], v1 = src[1], v2 = src[2], v3 = src[3];
        float f[16] = {v0.x, v0.y, v0.z, v0.w, v1.x, v1.y, v1.z, v1.w,
                       v2.x, v2.y, v2.z, v2.w, v3.x, v3.y, v3.z, v3.w};

        float ss = 0.f;
        #pragma unroll
        for (int m = 0; m < 16; ++m) ss += f[m] * f[m];   // exact ||e||^2

        // two 8B pieces: piece (kk = s>>1, quad = (s&1)*2 + qq), qq in {0,1}
        int kk = s >> 1;
        int q0 = (s & 1) * 2;
        uint2 pc0, pc1;
        pc0.x = pk4_fp8(f[0]*1024.f,  f[1]*1024.f,  f[2]*1024.f,  f[3]*1024.f);
        pc0.y = pk4_fp8(f[4]*1024.f,  f[5]*1024.f,  f[6]*1024.f,  f[7]*1024.f);
        pc1.x = pk4_fp8(f[8]*1024.f,  f[9]*1024.f,  f[10]*1024.f, f[11]*1024.f);
        pc1.y = pk4_fp8(f[12]*1024.f, f[13]*1024.f, f[14]*1024.f, f[15]*1024.f);
        uint2* dst = reinterpret_cast<uint2*>(ef8);
        dst[((size_t)k16 * 8 + kk) * 64 + (q0 + 0) * 16 + kr] = pc0;
        dst[((size_t)k16 * 8 + kk) * 64 + (q0 + 1) * 16 + kr] = pc1;

        #pragma unroll
        for (int off = 1; off < 16; off <<= 1) ss += __shfl_xor(ss, off);
        if (s == 0) enorm[code] = ss;
    } else {
        // ---- x copy + transpose-convert: 32 channels (one kk) x 256 hw ----
        int bid2 = bid - 64;
        int b  = bid2 >> 5;
        int kk = (bid2 >> 2) & 7;     // channel tile == fragment kk
        int ht = bid2 & 3;
        int c0  = kk * 32;
        int hw0 = ht * 256;

        const float* xb = x   + (size_t)b * (EMBED_DIM * HW) + hw0 + t;
        float*       ob = out + (size_t)b * (EMBED_DIM * HW) + hw0 + t;

        float f[32];
        float acc = 0.f;
        #pragma unroll
        for (int i = 0; i < 32; ++i) {
            float v = xb[(size_t)(c0 + i) * HW];
            ob[(size_t)(c0 + i) * HW] = v;
            acc += v * v;
            f[i] = v;
        }

        int n = b * HW + hw0 + t;
        int n16 = n >> 4;
        int l16 = t & 15;
        uint2* dst = reinterpret_cast<uint2*>(xf8);
        #pragma unroll
        for (int q = 0; q < 4; ++q) {
            uint2 p;
            p.x = pk4_fp8(f[8*q+0], f[8*q+1], f[8*q+2], f[8*q+3]);
            p.y = pk4_fp8(f[8*q+4], f[8*q+5], f[8*q+6], f[8*q+7]);
            dst[((size_t)n16 * 8 + kk) * 64 + q * 16 + l16] = p;
        }

        #pragma unroll
        for (int off = 32; off; off >>= 1) acc += __shfl_down(acc, off);
        if ((t & 63) == 0) wsum[t >> 6] = acc;
        __syncthreads();
        if (t == 0) psumA[bid2] = wsum[0] + wsum[1] + wsum[2] + wsum[3];
    }
}

// ---------------------------------------------------------------------------
// K2: fp8-MFMA min-distance + final reduction in last block.
// 256 blocks x 4 waves. Block = 128 rows. Wave w: rows (w>>1)*64..+63,
// code-half h = w&1 of each 128-code chunk (8 chunks, double-buffered LDS).
// A fragments (64 rows x 256 k) live in registers (64 VGPRs as 32x long).
// ---------------------------------------------------------------------------
__global__ __launch_bounds__(256) void k_argmin(
        const uint8_t* __restrict__ xf8, const uint8_t* __restrict__ ef8,
        const float* __restrict__ enorm, const float* __restrict__ psumA,
        float* __restrict__ psumB, int* __restrict__ ticket,
        float* __restrict__ loss_out) {
    __shared__ uint8_t Es[2][32768];   // 2 x 32KB: 128 codes x 256 k (fp8 frags)
    __shared__ float en_s[NUM_EMBED];
    __shared__ float red[128][2];
    __shared__ float fin[4];
    __shared__ double wsd[4];
    __shared__ int last;

    int t = threadIdx.x;
    int w = t >> 6, lane = t & 63;
    int l16 = lane & 15, quad = lane >> 4;
    int h = w & 1, rg = w >> 1;
    int rbase = blockIdx.x * 128 + rg * 64;

    #pragma unroll
    for (int i = 0; i < 4; ++i) en_s[t + i * 256] = enorm[t + i * 256];

    // A fragments: 4 row-tiles x 8 kk, 8B each
    long a[4][8];
    const long* xsrc = reinterpret_cast<const long*>(xf8);
    #pragma unroll
    for (int rt = 0; rt < 4; ++rt) {
        size_t n16 = (size_t)(rbase >> 4) + rt;
        #pragma unroll
        for (int kk = 0; kk < 8; ++kk)
            a[rt][kk] = xsrc[(n16 * 8 + kk) * 64 + lane];
    }

    // stage chunk 0 (32KB)
    {
        char* ldst = (char*)&Es[0][0];
        #pragma unroll
        for (int i = 0; i < 8; ++i) {
            int off = (i * 256 + t) * 16;
            gl_lds16((const char*)ef8 + off, ldst + off);
        }
    }
    __syncthreads();

    float dmin[4][4];
    #pragma unroll
    for (int rt = 0; rt < 4; ++rt)
        #pragma unroll
        for (int r = 0; r < 4; ++r) dmin[rt][r] = 1e30f;

    for (int s = 0; s < 8; ++s) {
        if (s + 1 < 8) {   // prefetch next chunk (drained by end-of-step barrier)
            const char* src = (const char*)ef8 + (size_t)(s + 1) * 32768;
            char* ldst = (char*)&Es[(s + 1) & 1][0];
            #pragma unroll
            for (int i = 0; i < 8; ++i) {
                int off = (i * 256 + t) * 16;
                gl_lds16(src + off, ldst + off);
            }
        }

        const uint8_t* buf = &Es[s & 1][0];
        f32x4 acc[4][4];
        #pragma unroll
        for (int rt = 0; rt < 4; ++rt)
            #pragma unroll
            for (int ct = 0; ct < 4; ++ct) {
                f32x4 z = {0.f, 0.f, 0.f, 0.f};
                acc[rt][ct] = z;
            }

        #pragma unroll
        for (int kk = 0; kk < 8; ++kk) {
            long bfr[4];
            #pragma unroll
            for (int ct = 0; ct < 4; ++ct)
                bfr[ct] = *reinterpret_cast<const long*>(
                    buf + ((((h * 4 + ct) * 8 + kk) * 64 + lane) << 3));
            #pragma unroll
            for (int rt = 0; rt < 4; ++rt)
                #pragma unroll
                for (int ct = 0; ct < 4; ++ct)
                    acc[rt][ct] = __builtin_amdgcn_mfma_f32_16x16x32_fp8_fp8(
                        a[rt][kk], bfr[ct], acc[rt][ct], 0, 0, 0);
        }

        // dist = ||e||^2 - 2*(dot/1024); code = s*128 + h*64 + ct*16 + l16
        #pragma unroll
        for (int ct = 0; ct < 4; ++ct) {
            float en = en_s[s * 128 + h * 64 + ct * 16 + l16];
            #pragma unroll
            for (int rt = 0; rt < 4; ++rt)
                #pragma unroll
                for (int r = 0; r < 4; ++r)
                    dmin[rt][r] = fminf(dmin[rt][r],
                                        fmaf(acc[rt][ct][r], -0.001953125f, en));
        }
        __syncthreads();
    }

    // min across the 16 l16-lanes sharing each row
    #pragma unroll
    for (int rt = 0; rt < 4; ++rt)
        #pragma unroll
        for (int r = 0; r < 4; ++r) {
            float v = dmin[rt][r];
            v = fminf(v, __shfl_xor(v, 1));
            v = fminf(v, __shfl_xor(v, 2));
            v = fminf(v, __shfl_xor(v, 4));
            v = fminf(v, __shfl_xor(v, 8));
            dmin[rt][r] = v;
        }

    if (l16 == 0) {
        #pragma unroll
        for (int rt = 0; rt < 4; ++rt)
            #pragma unroll
            for (int r = 0; r < 4; ++r)
                red[rg * 64 + rt * 16 + quad * 4 + r][h] = dmin[rt][r];
    }
    __syncthreads();

    // combine code-halves, sum the 128 row-mins
    float sblk = 0.f;
    if (t < 128) sblk = fminf(red[t][0], red[t][1]);
    #pragma unroll
    for (int off = 1; off < 64; off <<= 1) sblk += __shfl_xor(sblk, off);
    if (lane == 0) fin[w] = sblk;
    __syncthreads();

    if (t == 0) {
        psumB[blockIdx.x] = fin[0] + fin[1] + fin[2] + fin[3];
        __threadfence();
        int old = atomicAdd(ticket, 1);
        if (old == ARG_BLOCKS - 1) { __threadfence(); last = 1; }
        else last = 0;
    }
    __syncthreads();

    if (last) {   // last block: final reduction + loss write
        const volatile float* vA = psumA;
        const volatile float* vB = psumB;
        double sd = (double)vA[t] + (double)vA[t + 256]
                  + (double)vA[t + 512] + (double)vA[t + 768]
                  + (double)vB[t];
        #pragma unroll
        for (int off = 1; off < 64; off <<= 1) sd += __shfl_xor(sd, off);
        if (lane == 0) wsd[w] = sd;
        __syncthreads();
        if (t == 0)
            loss_out[0] = (float)(1.25 * (wsd[0] + wsd[1] + wsd[2] + wsd[3])
                                  / (double)OUT_ELEMS);
    }
}

extern "C" void kernel_launch(void* const* d_in, const int* in_sizes, int n_in,
                              void* d_out, int out_size, void* d_ws, size_t ws_size,
                              hipStream_t stream) {
    const float* x  = (const float*)d_in[0];   // [32,256,32,32] fp32
    const float* cb = (const float*)d_in[1];   // [1024,256] fp32
    float* out = (float*)d_out;                // 8388608 out + 1 loss

    char* ws = (char*)d_ws;
    float*   psumA  = (float*)ws;                   // 4 KB (1024)
    float*   psumB  = (float*)(ws + 4096);          // 1 KB (256)
    float*   enorm  = (float*)(ws + 8192);          // 4 KB
    int*     ticket = (int*)(ws + 12288);
    uint8_t* ef8    = (uint8_t*)(ws + 16384);       // 256 KB
    uint8_t* xf8    = (uint8_t*)(ws + 1048576);     // 8 MB

    hipLaunchKernelGGL(k_prep,   dim3(1088), dim3(256), 0, stream,
                       x, cb, out, ef8, enorm, xf8, psumA, ticket);
    hipLaunchKernelGGL(k_argmin, dim3(ARG_BLOCKS), dim3(256), 0, stream,
                       xf8, ef8, enorm, psumA, psumB, ticket, out + OUT_ELEMS);
}